// Round 5
// baseline (215.843 us; speedup 1.0000x reference)
//
#include <hip/hip_runtime.h>
#include <hip/hip_fp16.h>
#include <cstdint>

// ---------------- workspace layout (bytes) ----------------
static constexpr size_t OFF_XT   = 0;                                   // fp16 xT [b][hw][c] packed u32 pairs, 16 MB
static constexpr size_t OFF_HIAL = 16777216;                            // f32 hi_al [b][c][hw] 32 MB
static constexpr size_t OFF_PART = OFF_HIAL;                            // ALIAS: part [18][b][32][4096] f32 (18.9 MB)
                                                                        // safe: k_meta consumes part before k_dcn writes hial
static constexpr size_t OFF_MW   = OFF_HIAL + 33554432;                 // float4 meta weights [b][9][4096]
static constexpr size_t OFF_MI   = OFF_MW  + 2ull*9*4096*16;            // int4 meta indices
static constexpr size_t OFF_WA   = OFF_MI  + 2ull*9*4096*16;            // fp16 wA [9][32oc][1024c] u32-packed (offconv)
static constexpr size_t OFF_WB   = OFF_WA  + 9ull*32*512*4;             // fp16 wB [32g][9p][32o][32i] u32-packed (dcn)
// end ~= 51.4 MB

using f16x8 = __attribute__((ext_vector_type(8))) _Float16;
typedef __attribute__((ext_vector_type(4))) float f32x4;

__device__ __forceinline__ uint16_t f2h(float f) { return __half_as_ushort(__float2half(f)); }
__device__ __forceinline__ __half2 u2h(uint32_t u) { union { uint32_t u; __half2 h; } x; x.u = u; return x.h; }
__device__ __forceinline__ uint32_t h2u(__half2 h) { union { uint32_t u; __half2 h; } x; x.h = h; return x.u; }

// bilinear blend of 4 gathered corner words (8 fp16 channels) -> f16x8 MFMA B-fragment
__device__ __forceinline__ f16x8 blend4(uint4 A, uint4 B, uint4 C, uint4 D, float4 wv) {
    __half2 h00 = __float2half2_rn(wv.x), h01 = __float2half2_rn(wv.y);
    __half2 h10 = __float2half2_rn(wv.z), h11 = __float2half2_rn(wv.w);
    const uint32_t* a = (const uint32_t*)&A;
    const uint32_t* b = (const uint32_t*)&B;
    const uint32_t* c = (const uint32_t*)&C;
    const uint32_t* d = (const uint32_t*)&D;
    union { uint32_t u[4]; f16x8 v; } r;
#pragma unroll
    for (int e = 0; e < 4; ++e) {
        __half2 acc = __hmul2(h00, u2h(a[e]));
        acc = __hfma2(h01, u2h(b[e]), acc);
        acc = __hfma2(h10, u2h(c[e]), acc);
        acc = __hfma2(h11, u2h(d[e]), acc);
        r.u[e] = h2u(acc);
    }
    return r.v;
}

// ---------------- prep: weight transposes ----------------
__global__ void k_prep_wa(const float* __restrict__ w_off, uint32_t* __restrict__ wa) {
    int idx = blockIdx.x * 256 + threadIdx.x;              // 9*32*512
    if (idx >= 9 * 32 * 512) return;
    int p = idx / (32 * 512), r = idx % (32 * 512), oc = r / 512, cp = r % 512;
    uint32_t lo = 0, hi = 0;
    if (oc < 27) {
        lo = f2h(w_off[(size_t)oc * 9216 + (size_t)(cp * 2) * 9 + p]);
        hi = f2h(w_off[(size_t)oc * 9216 + (size_t)(cp * 2 + 1) * 9 + p]);
    }
    wa[idx] = lo | (hi << 16);
}

// wb[g][p][o][i] fp16 packed: [32][9][32][16] u32
__global__ void k_prep_wb(const float* __restrict__ w_dcn, uint32_t* __restrict__ wb) {
    int idx = blockIdx.x * 256 + threadIdx.x;              // 32*9*32*16
    if (idx >= 32 * 9 * 32 * 16) return;
    int g = idx / (9 * 32 * 16), r = idx % (9 * 32 * 16);
    int p = r / (32 * 16), r2 = r % (32 * 16), o = r2 / 16, ip = r2 % 16;
    uint32_t lo = f2h(w_dcn[((size_t)(g * 32 + o) * 32 + 2 * ip) * 9 + p]);
    uint32_t hi = f2h(w_dcn[((size_t)(g * 32 + o) * 32 + 2 * ip + 1) * 9 + p]);
    wb[idx] = lo | (hi << 16);
}

// ---------------- K0: hi_res NCHW f32 -> NHWC fp16 (packed pairs) ----------------
__global__ void k_transpose(const float* __restrict__ x, uint32_t* __restrict__ xt) {
    __shared__ float tile[64][65];
    int cblk = blockIdx.x * 64, y = blockIdx.y, b = blockIdx.z, t = threadIdx.x;
    const float* src = x + ((size_t)(b * 1024 + cblk)) * 4096 + y * 64;
#pragma unroll
    for (int k = 0; k < 16; ++k) {
        int lin = t + k * 256;
        int cl = lin >> 6, xx = lin & 63;
        tile[cl][xx] = src[(size_t)cl * 4096 + xx];
    }
    __syncthreads();
    uint32_t* dst = xt + ((size_t)b * 4096 + y * 64) * 512 + (cblk >> 1);
#pragma unroll
    for (int k = 0; k < 8; ++k) {
        int lin = t + k * 256;
        int xx = lin >> 5, cp = lin & 31;
        uint32_t lo = f2h(tile[2 * cp][xx]);
        uint32_t hi = f2h(tile[2 * cp + 1][xx]);
        dst[(size_t)xx * 512 + cp] = lo | (hi << 16);
    }
}

// ---------------- K1: offset conv via MFMA (fp16), 9 shifts x 2 K-halves ----------------
__global__ __launch_bounds__(256) void k_offconv_mfma(const uint32_t* __restrict__ xt,
                                                      const uint32_t* __restrict__ wa,
                                                      float* __restrict__ part) {
    int sp = blockIdx.x;                       // 0..17: shift p = sp>>1, K-half = sp&1
    int p = sp >> 1, kh = sp & 1;
    int y = blockIdx.y;
    int b = blockIdx.z;
    int t = threadIdx.x;
    int wave = t >> 6, lane = t & 63;
    int col = lane & 15, kg = lane >> 4;
    int x = wave * 16 + col;
    int ky = p / 3 - 1, kx = p % 3 - 1;
    int ys = y + ky, xs = x + kx;
    bool ok = (ys >= 0) && (ys < 64) && (xs >= 0) && (xs < 64);
    int ps = ok ? (ys * 64 + xs) : 0;

    const uint32_t* bp = xt + (size_t)b * 4096 * 512 + (size_t)ps * 512 + kh * 256 + kg * 4;
    const uint32_t* a0 = wa + ((size_t)p * 32 + col) * 512 + kh * 256 + kg * 4;
    const uint32_t* a1 = a0 + 16 * 512;

    f32x4 acc0 = {0.f, 0.f, 0.f, 0.f};
    f32x4 acc1 = {0.f, 0.f, 0.f, 0.f};
#pragma unroll 4
    for (int ks = 0; ks < 16; ++ks) {
        f16x8 bfrag = {0, 0, 0, 0, 0, 0, 0, 0};
        if (ok) bfrag = *(const f16x8*)(bp + ks * 16);
        f16x8 af0 = *(const f16x8*)(a0 + ks * 16);
        f16x8 af1 = *(const f16x8*)(a1 + ks * 16);
        acc0 = __builtin_amdgcn_mfma_f32_16x16x32_f16(af0, bfrag, acc0, 0, 0, 0);
        acc1 = __builtin_amdgcn_mfma_f32_16x16x32_f16(af1, bfrag, acc1, 0, 0, 0);
    }
    float* pc = part + ((size_t)(sp * 2 + b)) * 32 * 4096 + (size_t)y * 64 + wave * 16 + col;
#pragma unroll
    for (int j = 0; j < 4; ++j) {
        pc[(size_t)(kg * 4 + j) * 4096]      = acc0[j];
        pc[(size_t)(16 + kg * 4 + j) * 4096] = acc1[j];
    }
}

// ---------------- K2: reduce 18 partials -> sampling meta ----------------
__global__ void k_meta(const float* __restrict__ part, const float* __restrict__ b_off,
                       float4* __restrict__ mw, int4* __restrict__ mi) {
    int idx = blockIdx.x * 256 + threadIdx.x;              // 2*9*4096
    if (idx >= 2 * 9 * 4096) return;
    int b = idx / (9 * 4096), r = idx % (9 * 4096), p = r / 4096, hw = r % 4096;
    int h = hw >> 6, w = hw & 63;
    float sdy = b_off[p], sdx = b_off[p + 9], sm = b_off[p + 18];
#pragma unroll
    for (int s = 0; s < 18; ++s) {
        const float* pb = part + ((size_t)(s * 2 + b)) * 32 * 4096 + hw;
        sdy += pb[(size_t)p * 4096];
        sdx += pb[(size_t)(p + 9) * 4096];
        sm  += pb[(size_t)(p + 18) * 4096];
    }
    float m = 1.f / (1.f + expf(-sm));
    int ky = p / 3 - 1, kx = p % 3 - 1;
    float sy = (float)(h + ky) + sdy;
    float sx = (float)(w + kx) + sdx;
    float y0f = floorf(sy), x0f = floorf(sx);
    float wy = sy - y0f, wx = sx - x0f;
    int y0 = (int)fminf(fmaxf(y0f, -2.f), 64.f);
    int x0 = (int)fminf(fmaxf(x0f, -2.f), 64.f);
    bool vy0 = (y0 >= 0) && (y0 < 64), vy1 = (y0 + 1 >= 0) && (y0 + 1 < 64);
    bool vx0 = (x0 >= 0) && (x0 < 64), vx1 = (x0 + 1 >= 0) && (x0 + 1 < 64);
    float w00 = (1.f - wy) * (1.f - wx) * m * ((vy0 && vx0) ? 1.f : 0.f);
    float w01 = (1.f - wy) * wx         * m * ((vy0 && vx1) ? 1.f : 0.f);
    float w10 = wy * (1.f - wx)         * m * ((vy1 && vx0) ? 1.f : 0.f);
    float w11 = wy * wx                 * m * ((vy1 && vx1) ? 1.f : 0.f);
    int cy0 = min(max(y0, 0), 63),     cx0 = min(max(x0, 0), 63);
    int cy1 = min(max(y0 + 1, 0), 63), cx1 = min(max(x0 + 1, 0), 63);
    mw[idx] = float4{w00, w01, w10, w11};
    mi[idx] = int4{cy0 * 64 + cx0, cy0 * 64 + cx1, cy1 * 64 + cx0, cy1 * 64 + cx1};
}

// ---------------- K3: deformable sample + grouped conv via MFMA ----------------
// 1 px per lane-column, fp16 pk blend, ping-pong gather pipeline (tap p+1 loads in
// flight across tap p's blend+MFMA; meta prefetched one tap ahead of the gathers).
__global__ __launch_bounds__(256, 4) void k_dcn_mfma(const uint32_t* __restrict__ xt,
                                                     const uint32_t* __restrict__ wb,
                                                     const float4* __restrict__ mw,
                                                     const int4* __restrict__ mi,
                                                     const float* __restrict__ b_dcn,
                                                     float* __restrict__ hial) {
    int g = blockIdx.x, y = blockIdx.y, b = blockIdx.z;
    int t = threadIdx.x, wave = t >> 6, lane = t & 63;
    int col = lane & 15, kg = lane >> 4;
    int pix = y * 64 + wave * 16 + col;

    const uint32_t* xb = xt + (size_t)b * 4096 * 512 + g * 16 + kg * 4;
    const uint32_t* wg = wb + (size_t)g * 9 * 32 * 16 + col * 16 + kg * 4;
    const float4* mwb = mw + (size_t)b * 9 * 4096;
    const int4*   mib = mi + (size_t)b * 9 * 4096;

    f32x4 acc0 = {0.f, 0.f, 0.f, 0.f};
    f32x4 acc1 = {0.f, 0.f, 0.f, 0.f};

    // prologue: tap 0 meta + gathers, tap 1 meta
    float4 wcur = mwb[pix];
    int4 icur = mib[pix];
    uint4 A0 = *(const uint4*)(xb + (size_t)icur.x * 512);
    uint4 A1 = *(const uint4*)(xb + (size_t)icur.y * 512);
    uint4 A2 = *(const uint4*)(xb + (size_t)icur.z * 512);
    uint4 A3 = *(const uint4*)(xb + (size_t)icur.w * 512);
    float4 wnxt = mwb[4096 + pix];
    int4   inxt = mib[4096 + pix];

#define TAP(P, C0, C1, C2, C3, N0, N1, N2, N3)                                    \
    {                                                                             \
        if ((P) < 8) {                                                            \
            N0 = *(const uint4*)(xb + (size_t)inxt.x * 512);                      \
            N1 = *(const uint4*)(xb + (size_t)inxt.y * 512);                      \
            N2 = *(const uint4*)(xb + (size_t)inxt.z * 512);                      \
            N3 = *(const uint4*)(xb + (size_t)inxt.w * 512);                      \
        }                                                                         \
        float4 wv = wcur;                                                         \
        if ((P) < 7) {                                                            \
            wcur = wnxt;                                                          \
            wnxt = mwb[((P) + 2) * 4096 + pix];                                   \
            inxt = mib[((P) + 2) * 4096 + pix];                                   \
        } else if ((P) == 7) { wcur = wnxt; }                                     \
        f16x8 bfr = blend4(C0, C1, C2, C3, wv);                                   \
        const uint32_t* ap = wg + (size_t)(P) * 32 * 16;                          \
        f16x8 af0 = *(const f16x8*)ap;                                            \
        f16x8 af1 = *(const f16x8*)(ap + 16 * 16);                                \
        acc0 = __builtin_amdgcn_mfma_f32_16x16x32_f16(af0, bfr, acc0, 0, 0, 0);   \
        acc1 = __builtin_amdgcn_mfma_f32_16x16x32_f16(af1, bfr, acc1, 0, 0, 0);   \
    }

    uint4 B0, B1, B2, B3;
    TAP(0, A0, A1, A2, A3, B0, B1, B2, B3)
    TAP(1, B0, B1, B2, B3, A0, A1, A2, A3)
    TAP(2, A0, A1, A2, A3, B0, B1, B2, B3)
    TAP(3, B0, B1, B2, B3, A0, A1, A2, A3)
    TAP(4, A0, A1, A2, A3, B0, B1, B2, B3)
    TAP(5, B0, B1, B2, B3, A0, A1, A2, A3)
    TAP(6, A0, A1, A2, A3, B0, B1, B2, B3)
    TAP(7, B0, B1, B2, B3, A0, A1, A2, A3)
    TAP(8, A0, A1, A2, A3, B0, B1, B2, B3)
#undef TAP

    const float* bd = b_dcn + g * 32;
    float* pc = hial + ((size_t)b * 1024 + g * 32) * 4096 + pix;
#pragma unroll
    for (int j = 0; j < 4; ++j) {
        pc[(size_t)(kg * 4 + j) * 4096]      = acc0[j] + bd[kg * 4 + j];
        pc[(size_t)(16 + kg * 4 + j) * 4096] = acc1[j] + bd[16 + kg * 4 + j];
    }
}

// ---------------- K4: fused bilinear 2x upsample + grouped 1x1 conv ----------------
__global__ __launch_bounds__(256) void k_post(const float* __restrict__ lo,
                                              const float* __restrict__ hial,
                                              const float* __restrict__ wp,
                                              const float* __restrict__ bp,
                                              float* __restrict__ out) {
    int gb = blockIdx.x, h = blockIdx.y, b = blockIdx.z, t = threadIdx.x;
    int w = t & 63, gl = t >> 6;
    int g = gb * 4 + gl;
    float fy = 0.5f * h - 0.25f; float fy0 = floorf(fy); float ty = fy - fy0;
    int r0 = (int)fy0; int r1 = r0 + 1; r0 = r0 < 0 ? 0 : r0; r1 = r1 > 31 ? 31 : r1;
    float fx = 0.5f * w - 0.25f; float fx0 = floorf(fx); float tx = fx - fx0;
    int c0 = (int)fx0; int c1 = c0 + 1; c0 = c0 < 0 ? 0 : c0; c1 = c1 > 31 ? 31 : c1;
    float v[12];
    int cbase = g * 12;
#pragma unroll
    for (int i = 0; i < 12; ++i) {
        int c = cbase + i;
        if (c < 2048) {
            const float* lb = lo + ((size_t)(b * 2048 + c)) * 1024;
            float a00 = lb[r0 * 32 + c0], a01 = lb[r0 * 32 + c1];
            float a10 = lb[r1 * 32 + c0], a11 = lb[r1 * 32 + c1];
            v[i] = (1.f - ty) * ((1.f - tx) * a00 + tx * a01)
                 + ty * ((1.f - tx) * a10 + tx * a11);
        } else {
            v[i] = hial[((size_t)b * 1024 + (c - 2048)) * 4096 + h * 64 + w];
        }
    }
    const float* wrow = wp + (size_t)g * 96;
    float* ob_ = out + ((size_t)b * 2048 + g * 8) * 4096 + h * 64 + w;
#pragma unroll
    for (int o = 0; o < 8; ++o) {
        float s = bp[g * 8 + o];
#pragma unroll
        for (int i = 0; i < 12; ++i) s += wrow[o * 12 + i] * v[i];
        ob_[(size_t)o * 4096] = s;
    }
}

extern "C" void kernel_launch(void* const* d_in, const int* in_sizes, int n_in,
                              void* d_out, int out_size, void* d_ws, size_t ws_size,
                              hipStream_t stream) {
    const float* lo_res = (const float*)d_in[0];
    const float* hi_res = (const float*)d_in[1];
    const float* w_off  = (const float*)d_in[2];
    const float* b_off  = (const float*)d_in[3];
    const float* w_dcn  = (const float*)d_in[4];
    const float* b_dcn  = (const float*)d_in[5];
    const float* w_post = (const float*)d_in[6];
    const float* b_post = (const float*)d_in[7];
    float* out = (float*)d_out;
    char* ws = (char*)d_ws;

    uint32_t* xt  = (uint32_t*)(ws + OFF_XT);
    float* hial   = (float*)(ws + OFF_HIAL);
    float* part   = (float*)(ws + OFF_PART);     // aliases hial region (consumed before hial written)
    float4* mwp   = (float4*)(ws + OFF_MW);
    int4* mip     = (int4*)(ws + OFF_MI);
    uint32_t* wa  = (uint32_t*)(ws + OFF_WA);
    uint32_t* wbp = (uint32_t*)(ws + OFF_WB);

    k_prep_wa<<<(9 * 32 * 512 + 255) / 256, 256, 0, stream>>>(w_off, wa);
    k_prep_wb<<<(32 * 9 * 32 * 16 + 255) / 256, 256, 0, stream>>>(w_dcn, wbp);
    k_transpose<<<dim3(16, 64, 2), 256, 0, stream>>>(hi_res, xt);
    k_offconv_mfma<<<dim3(18, 64, 2), 256, 0, stream>>>(xt, wa, part);
    k_meta<<<(2 * 9 * 4096 + 255) / 256, 256, 0, stream>>>(part, b_off, mwp, mip);
    k_dcn_mfma<<<dim3(32, 64, 2), 256, 0, stream>>>(xt, wbp, mwp, mip, b_dcn, hial);
    k_post<<<dim3(64, 64, 2), 256, 0, stream>>>(lo_res, hial, w_post, b_post, out);
}

// Round 6
// 179.338 us; speedup vs baseline: 1.2036x; 1.2036x over previous
//
#include <hip/hip_runtime.h>
#include <hip/hip_fp16.h>
#include <cstdint>

// ---------------- workspace layout (bytes) ----------------
static constexpr size_t OFF_XT   = 0;                                   // fp16 xT [b][hw][c] packed u32 pairs, 16 MB
static constexpr size_t OFF_HIAL = 16777216;                            // f32 hi_al [b][c][hw] 32 MB
static constexpr size_t OFF_PART = OFF_HIAL;                            // ALIAS: part [18][b][32][4096] f32 (18.9 MB)
                                                                        // safe: k_meta consumes part before k_dcn writes hial
static constexpr size_t OFF_MW   = OFF_HIAL + 33554432;                 // float4 meta weights [b][9][4096]
static constexpr size_t OFF_MI   = OFF_MW  + 2ull*9*4096*16;            // int4 meta indices
static constexpr size_t OFF_WA   = OFF_MI  + 2ull*9*4096*16;            // fp16 wA [9][32oc][1024c] u32-packed (offconv)
static constexpr size_t OFF_WB   = OFF_WA  + 9ull*32*512*4;             // fp16 wB [32g][9p][32o][32i] u32-packed (dcn)
// end ~= 51.4 MB

using f16x8 = __attribute__((ext_vector_type(8))) _Float16;
typedef __attribute__((ext_vector_type(4))) float f32x4;

__device__ __forceinline__ uint16_t f2h(float f) { return __half_as_ushort(__float2half(f)); }
__device__ __forceinline__ __half2 u2h(uint32_t u) { union { uint32_t u; __half2 h; } x; x.u = u; return x.h; }
__device__ __forceinline__ uint32_t h2u(__half2 h) { union { uint32_t u; __half2 h; } x; x.h = h; return x.u; }

// bilinear blend of 4 gathered corner words (8 fp16 channels) -> f16x8 MFMA B-fragment
__device__ __forceinline__ f16x8 blend4(uint4 A, uint4 B, uint4 C, uint4 D, float4 wv) {
    __half2 h00 = __float2half2_rn(wv.x), h01 = __float2half2_rn(wv.y);
    __half2 h10 = __float2half2_rn(wv.z), h11 = __float2half2_rn(wv.w);
    const uint32_t* a = (const uint32_t*)&A;
    const uint32_t* b = (const uint32_t*)&B;
    const uint32_t* c = (const uint32_t*)&C;
    const uint32_t* d = (const uint32_t*)&D;
    union { uint32_t u[4]; f16x8 v; } r;
#pragma unroll
    for (int e = 0; e < 4; ++e) {
        __half2 acc = __hmul2(h00, u2h(a[e]));
        acc = __hfma2(h01, u2h(b[e]), acc);
        acc = __hfma2(h10, u2h(c[e]), acc);
        acc = __hfma2(h11, u2h(d[e]), acc);
        r.u[e] = h2u(acc);
    }
    return r.v;
}

// ---------------- prep: weight transposes ----------------
__global__ void k_prep_wa(const float* __restrict__ w_off, uint32_t* __restrict__ wa) {
    int idx = blockIdx.x * 256 + threadIdx.x;              // 9*32*512
    if (idx >= 9 * 32 * 512) return;
    int p = idx / (32 * 512), r = idx % (32 * 512), oc = r / 512, cp = r % 512;
    uint32_t lo = 0, hi = 0;
    if (oc < 27) {
        lo = f2h(w_off[(size_t)oc * 9216 + (size_t)(cp * 2) * 9 + p]);
        hi = f2h(w_off[(size_t)oc * 9216 + (size_t)(cp * 2 + 1) * 9 + p]);
    }
    wa[idx] = lo | (hi << 16);
}

// wb[g][p][o][i] fp16 packed: [32][9][32][16] u32
__global__ void k_prep_wb(const float* __restrict__ w_dcn, uint32_t* __restrict__ wb) {
    int idx = blockIdx.x * 256 + threadIdx.x;              // 32*9*32*16
    if (idx >= 32 * 9 * 32 * 16) return;
    int g = idx / (9 * 32 * 16), r = idx % (9 * 32 * 16);
    int p = r / (32 * 16), r2 = r % (32 * 16), o = r2 / 16, ip = r2 % 16;
    uint32_t lo = f2h(w_dcn[((size_t)(g * 32 + o) * 32 + 2 * ip) * 9 + p]);
    uint32_t hi = f2h(w_dcn[((size_t)(g * 32 + o) * 32 + 2 * ip + 1) * 9 + p]);
    wb[idx] = lo | (hi << 16);
}

// ---------------- K0: hi_res NCHW f32 -> NHWC fp16 (packed pairs) ----------------
__global__ void k_transpose(const float* __restrict__ x, uint32_t* __restrict__ xt) {
    __shared__ float tile[64][65];
    int cblk = blockIdx.x * 64, y = blockIdx.y, b = blockIdx.z, t = threadIdx.x;
    const float* src = x + ((size_t)(b * 1024 + cblk)) * 4096 + y * 64;
#pragma unroll
    for (int k = 0; k < 16; ++k) {
        int lin = t + k * 256;
        int cl = lin >> 6, xx = lin & 63;
        tile[cl][xx] = src[(size_t)cl * 4096 + xx];
    }
    __syncthreads();
    uint32_t* dst = xt + ((size_t)b * 4096 + y * 64) * 512 + (cblk >> 1);
#pragma unroll
    for (int k = 0; k < 8; ++k) {
        int lin = t + k * 256;
        int xx = lin >> 5, cp = lin & 31;
        uint32_t lo = f2h(tile[2 * cp][xx]);
        uint32_t hi = f2h(tile[2 * cp + 1][xx]);
        dst[(size_t)xx * 512 + cp] = lo | (hi << 16);
    }
}

// ---------------- K1: offset conv via MFMA (fp16), 9 shifts x 2 K-halves ----------------
__global__ __launch_bounds__(256) void k_offconv_mfma(const uint32_t* __restrict__ xt,
                                                      const uint32_t* __restrict__ wa,
                                                      float* __restrict__ part) {
    int sp = blockIdx.x;                       // 0..17: shift p = sp>>1, K-half = sp&1
    int p = sp >> 1, kh = sp & 1;
    int y = blockIdx.y;
    int b = blockIdx.z;
    int t = threadIdx.x;
    int wave = t >> 6, lane = t & 63;
    int col = lane & 15, kg = lane >> 4;
    int x = wave * 16 + col;
    int ky = p / 3 - 1, kx = p % 3 - 1;
    int ys = y + ky, xs = x + kx;
    bool ok = (ys >= 0) && (ys < 64) && (xs >= 0) && (xs < 64);
    int ps = ok ? (ys * 64 + xs) : 0;

    const uint32_t* bp = xt + (size_t)b * 4096 * 512 + (size_t)ps * 512 + kh * 256 + kg * 4;
    const uint32_t* a0 = wa + ((size_t)p * 32 + col) * 512 + kh * 256 + kg * 4;
    const uint32_t* a1 = a0 + 16 * 512;

    f32x4 acc0 = {0.f, 0.f, 0.f, 0.f};
    f32x4 acc1 = {0.f, 0.f, 0.f, 0.f};
#pragma unroll 4
    for (int ks = 0; ks < 16; ++ks) {
        f16x8 bfrag = {0, 0, 0, 0, 0, 0, 0, 0};
        if (ok) bfrag = *(const f16x8*)(bp + ks * 16);
        f16x8 af0 = *(const f16x8*)(a0 + ks * 16);
        f16x8 af1 = *(const f16x8*)(a1 + ks * 16);
        acc0 = __builtin_amdgcn_mfma_f32_16x16x32_f16(af0, bfrag, acc0, 0, 0, 0);
        acc1 = __builtin_amdgcn_mfma_f32_16x16x32_f16(af1, bfrag, acc1, 0, 0, 0);
    }
    float* pc = part + ((size_t)(sp * 2 + b)) * 32 * 4096 + (size_t)y * 64 + wave * 16 + col;
#pragma unroll
    for (int j = 0; j < 4; ++j) {
        pc[(size_t)(kg * 4 + j) * 4096]      = acc0[j];
        pc[(size_t)(16 + kg * 4 + j) * 4096] = acc1[j];
    }
}

// ---------------- K2: reduce 18 partials -> sampling meta ----------------
__global__ void k_meta(const float* __restrict__ part, const float* __restrict__ b_off,
                       float4* __restrict__ mw, int4* __restrict__ mi) {
    int idx = blockIdx.x * 256 + threadIdx.x;              // 2*9*4096
    if (idx >= 2 * 9 * 4096) return;
    int b = idx / (9 * 4096), r = idx % (9 * 4096), p = r / 4096, hw = r % 4096;
    int h = hw >> 6, w = hw & 63;
    float sdy = b_off[p], sdx = b_off[p + 9], sm = b_off[p + 18];
#pragma unroll
    for (int s = 0; s < 18; ++s) {
        const float* pb = part + ((size_t)(s * 2 + b)) * 32 * 4096 + hw;
        sdy += pb[(size_t)p * 4096];
        sdx += pb[(size_t)(p + 9) * 4096];
        sm  += pb[(size_t)(p + 18) * 4096];
    }
    float m = 1.f / (1.f + expf(-sm));
    int ky = p / 3 - 1, kx = p % 3 - 1;
    float sy = (float)(h + ky) + sdy;
    float sx = (float)(w + kx) + sdx;
    float y0f = floorf(sy), x0f = floorf(sx);
    float wy = sy - y0f, wx = sx - x0f;
    int y0 = (int)fminf(fmaxf(y0f, -2.f), 64.f);
    int x0 = (int)fminf(fmaxf(x0f, -2.f), 64.f);
    bool vy0 = (y0 >= 0) && (y0 < 64), vy1 = (y0 + 1 >= 0) && (y0 + 1 < 64);
    bool vx0 = (x0 >= 0) && (x0 < 64), vx1 = (x0 + 1 >= 0) && (x0 + 1 < 64);
    float w00 = (1.f - wy) * (1.f - wx) * m * ((vy0 && vx0) ? 1.f : 0.f);
    float w01 = (1.f - wy) * wx         * m * ((vy0 && vx1) ? 1.f : 0.f);
    float w10 = wy * (1.f - wx)         * m * ((vy1 && vx0) ? 1.f : 0.f);
    float w11 = wy * wx                 * m * ((vy1 && vx1) ? 1.f : 0.f);
    int cy0 = min(max(y0, 0), 63),     cx0 = min(max(x0, 0), 63);
    int cy1 = min(max(y0 + 1, 0), 63), cx1 = min(max(x0 + 1, 0), 63);
    mw[idx] = float4{w00, w01, w10, w11};
    mi[idx] = int4{cy0 * 64 + cx0, cy0 * 64 + cx1, cy1 * 64 + cx0, cy1 * 64 + cx1};
}

// ---------------- K3: deformable sample + grouped conv, LDS-staged texture ----------------
// Block = (g, 8-row band, b). LDS holds a 20-row x 64-px x 64B slice of group g
// (covers all bilinear corners for |offset|<5; rare outliers take a global fallback).
// 16B-granule XOR swizzle (quad ^= slot&3) -> even 8-lanes-per-bank-quad on ds_read_b128.
__global__ __launch_bounds__(256, 2) void k_dcn_lds(const uint32_t* __restrict__ xt,
                                                    const uint32_t* __restrict__ wb,
                                                    const float4* __restrict__ mw,
                                                    const int4* __restrict__ mi,
                                                    const float* __restrict__ b_dcn,
                                                    float* __restrict__ hial) {
    __shared__ uint4 ldsq[5120];               // 20 rows * 64 px * 64 B = 80 KB
    int g = blockIdx.x, band = blockIdx.y, b = blockIdx.z;
    int y0 = band * 8;
    int band_lo = y0 - 6;
    if (band_lo < 0) band_lo = 0;
    if (band_lo > 44) band_lo = 44;
    int t = threadIdx.x;

    // fill: linear LDS dest, inverse-swizzled coalesced source
    {
        const uint32_t* src = xt + ((size_t)b * 4096 + (size_t)band_lo * 64) * 512 + g * 16;
#pragma unroll 4
        for (int i = 0; i < 20; ++i) {
            int Q = i * 256 + t;               // 16B-granule index
            int s = Q >> 2;                    // band slot (row-major pixel)
            int q = (Q & 3) ^ (s & 3);         // texture quad stored at this granule
            ldsq[Q] = *(const uint4*)(src + (size_t)s * 512 + q * 4);
        }
    }
    __syncthreads();
    const uint32_t* ldsb = (const uint32_t*)ldsq;

    int wave = t >> 6, lane = t & 63;
    int col = lane & 15, kg = lane >> 4;
    const uint32_t* xb = xt + (size_t)b * 4096 * 512 + g * 16 + kg * 4;   // fallback base
    const uint32_t* wg = wb + (size_t)g * 9 * 32 * 16 + col * 16 + kg * 4;
    const float4* mwb = mw + (size_t)b * 9 * 4096;
    const int4*   mib = mi + (size_t)b * 9 * 4096;
    const float*  bd  = b_dcn + g * 32;
    int blo64 = band_lo * 64;

#define GATHER(CP, U)                                                              \
    {                                                                              \
        int s_ = (CP) - blo64;                                                     \
        int sc_ = s_ < 0 ? 0 : (s_ > 1279 ? 1279 : s_);                            \
        U = *(const uint4*)(ldsb + sc_ * 16 + ((kg ^ (sc_ & 3)) << 2));            \
        if ((unsigned)s_ >= 1280u)                                                 \
            U = *(const uint4*)(xb + (size_t)(CP) * 512);                          \
    }

    for (int r = 0; r < 8; ++r) {
        int pix = (y0 + r) * 64 + wave * 16 + col;
        f32x4 acc0 = {0.f, 0.f, 0.f, 0.f};
        f32x4 acc1 = {0.f, 0.f, 0.f, 0.f};
#pragma unroll
        for (int p = 0; p < 9; ++p) {
            float4 wv = mwb[p * 4096 + pix];
            int4   iv = mib[p * 4096 + pix];
            uint4 u0, u1, u2, u3;
            GATHER(iv.x, u0)
            GATHER(iv.y, u1)
            GATHER(iv.z, u2)
            GATHER(iv.w, u3)
            f16x8 bfr = blend4(u0, u1, u2, u3, wv);
            const uint32_t* ap = wg + (size_t)p * 512;
            f16x8 af0 = *(const f16x8*)ap;
            f16x8 af1 = *(const f16x8*)(ap + 256);
            acc0 = __builtin_amdgcn_mfma_f32_16x16x32_f16(af0, bfr, acc0, 0, 0, 0);
            acc1 = __builtin_amdgcn_mfma_f32_16x16x32_f16(af1, bfr, acc1, 0, 0, 0);
        }
        float* pc = hial + ((size_t)b * 1024 + g * 32) * 4096 + pix;
#pragma unroll
        for (int j = 0; j < 4; ++j) {
            pc[(size_t)(kg * 4 + j) * 4096]      = acc0[j] + bd[kg * 4 + j];
            pc[(size_t)(16 + kg * 4 + j) * 4096] = acc1[j] + bd[16 + kg * 4 + j];
        }
    }
#undef GATHER
}

// ---------------- K4: fused bilinear 2x upsample + grouped 1x1 conv ----------------
__global__ __launch_bounds__(256) void k_post(const float* __restrict__ lo,
                                              const float* __restrict__ hial,
                                              const float* __restrict__ wp,
                                              const float* __restrict__ bp,
                                              float* __restrict__ out) {
    int gb = blockIdx.x, h = blockIdx.y, b = blockIdx.z, t = threadIdx.x;
    int w = t & 63, gl = t >> 6;
    int g = gb * 4 + gl;
    float fy = 0.5f * h - 0.25f; float fy0 = floorf(fy); float ty = fy - fy0;
    int r0 = (int)fy0; int r1 = r0 + 1; r0 = r0 < 0 ? 0 : r0; r1 = r1 > 31 ? 31 : r1;
    float fx = 0.5f * w - 0.25f; float fx0 = floorf(fx); float tx = fx - fx0;
    int c0 = (int)fx0; int c1 = c0 + 1; c0 = c0 < 0 ? 0 : c0; c1 = c1 > 31 ? 31 : c1;
    float v[12];
    int cbase = g * 12;
#pragma unroll
    for (int i = 0; i < 12; ++i) {
        int c = cbase + i;
        if (c < 2048) {
            const float* lb = lo + ((size_t)(b * 2048 + c)) * 1024;
            float a00 = lb[r0 * 32 + c0], a01 = lb[r0 * 32 + c1];
            float a10 = lb[r1 * 32 + c0], a11 = lb[r1 * 32 + c1];
            v[i] = (1.f - ty) * ((1.f - tx) * a00 + tx * a01)
                 + ty * ((1.f - tx) * a10 + tx * a11);
        } else {
            v[i] = hial[((size_t)b * 1024 + (c - 2048)) * 4096 + h * 64 + w];
        }
    }
    const float* wrow = wp + (size_t)g * 96;
    float* ob_ = out + ((size_t)b * 2048 + g * 8) * 4096 + h * 64 + w;
#pragma unroll
    for (int o = 0; o < 8; ++o) {
        float s = bp[g * 8 + o];
#pragma unroll
        for (int i = 0; i < 12; ++i) s += wrow[o * 12 + i] * v[i];
        ob_[(size_t)o * 4096] = s;
    }
}

extern "C" void kernel_launch(void* const* d_in, const int* in_sizes, int n_in,
                              void* d_out, int out_size, void* d_ws, size_t ws_size,
                              hipStream_t stream) {
    const float* lo_res = (const float*)d_in[0];
    const float* hi_res = (const float*)d_in[1];
    const float* w_off  = (const float*)d_in[2];
    const float* b_off  = (const float*)d_in[3];
    const float* w_dcn  = (const float*)d_in[4];
    const float* b_dcn  = (const float*)d_in[5];
    const float* w_post = (const float*)d_in[6];
    const float* b_post = (const float*)d_in[7];
    float* out = (float*)d_out;
    char* ws = (char*)d_ws;

    uint32_t* xt  = (uint32_t*)(ws + OFF_XT);
    float* hial   = (float*)(ws + OFF_HIAL);
    float* part   = (float*)(ws + OFF_PART);     // aliases hial region (consumed before hial written)
    float4* mwp   = (float4*)(ws + OFF_MW);
    int4* mip     = (int4*)(ws + OFF_MI);
    uint32_t* wa  = (uint32_t*)(ws + OFF_WA);
    uint32_t* wbp = (uint32_t*)(ws + OFF_WB);

    k_prep_wa<<<(9 * 32 * 512 + 255) / 256, 256, 0, stream>>>(w_off, wa);
    k_prep_wb<<<(32 * 9 * 32 * 16 + 255) / 256, 256, 0, stream>>>(w_dcn, wbp);
    k_transpose<<<dim3(16, 64, 2), 256, 0, stream>>>(hi_res, xt);
    k_offconv_mfma<<<dim3(18, 64, 2), 256, 0, stream>>>(xt, wa, part);
    k_meta<<<(2 * 9 * 4096 + 255) / 256, 256, 0, stream>>>(part, b_off, mwp, mip);
    k_dcn_lds<<<dim3(32, 8, 2), 256, 0, stream>>>(xt, wbp, mwp, mip, b_dcn, hial);
    k_post<<<dim3(64, 64, 2), 256, 0, stream>>>(lo_res, hial, w_post, b_post, out);
}